// Round 14
// baseline (338.490 us; speedup 1.0000x reference)
//
#include <hip/hip_runtime.h>

#define N_PTS 65536
#define BN_EPS 1e-5f
#define NSHD 64            // stat shadow copies
#define NSB  (10 * NSHD * 128)
#define HBLK 32            // histogram scan blocks (2048 bins each)
#define BINS_PER (N_PTS / HBLK)

typedef __attribute__((ext_vector_type(8))) short bf16x8;
typedef __attribute__((ext_vector_type(4))) float f32x4;

static __device__ __forceinline__ unsigned short f2bf(float f) {
    unsigned u = __builtin_bit_cast(unsigned, f);
    u += 0x7fffu + ((u >> 16) & 1u);          // round-to-nearest-even
    return (unsigned short)(u >> 16);
}
static __device__ __forceinline__ float bf2f(unsigned short h) {
    unsigned u = ((unsigned)h) << 16;
    return __builtin_bit_cast(float, u);
}
static __device__ __forceinline__ unsigned pack2(float a, float b) {
    return (unsigned)f2bf(a) | ((unsigned)f2bf(b) << 16);
}

// ---------------------------------------------------------------------------
// prep: (a) blocks [0,HBLK): replicated-scan histogram of ref — each block
// owns bins [b*2048, (b+1)*2048), scans ALL 1M refs with coalesced int4
// loads (L2-resident), LDS-atomic bins, plain-stores its exclusive range
// (no zeroing, no global atomics). (b) blocks [HBLK, ..): zero stat shadows.
__global__ __launch_bounds__(512) void prep_kernel(
    const int* __restrict__ ref, unsigned* __restrict__ cnt,
    float* __restrict__ Sb)
{
    const int b = blockIdx.x;
    const int tid = threadIdx.x;
    if (b < HBLK) {
        __shared__ unsigned bins[BINS_PER];
        const int lo = b * BINS_PER;
        for (int i = tid; i < BINS_PER; i += 512) bins[i] = 0u;
        __syncthreads();
        const int4* rp = (const int4*)ref;
        #pragma unroll 4
        for (int i = tid; i < (N_PTS * 16) / 4; i += 512) {
            int4 v = rp[i];
            unsigned x;
            x = (unsigned)(v.x - lo); if (x < (unsigned)BINS_PER) atomicAdd(&bins[x], 1u);
            x = (unsigned)(v.y - lo); if (x < (unsigned)BINS_PER) atomicAdd(&bins[x], 1u);
            x = (unsigned)(v.z - lo); if (x < (unsigned)BINS_PER) atomicAdd(&bins[x], 1u);
            x = (unsigned)(v.w - lo); if (x < (unsigned)BINS_PER) atomicAdd(&bins[x], 1u);
        }
        __syncthreads();
        for (int i = tid; i < BINS_PER; i += 512) cnt[lo + i] = bins[i];
    } else {
        const int zidx = (b - HBLK) * 512 + tid;
        const int ztot = (gridDim.x - HBLK) * 512;
        for (int i = zidx; i < NSB; i += ztot) Sb[i] = 0.f;
    }
}

// ---------------------------------------------------------------------------
// Fused (pre-op) -> 64x64 matmul (bf16x3 MFMA, ~fp32) -> (weighted) stats.
// Wave = 16 rows x 64 cols. Block = 4 waves = 64 rows. Grid = 1024 (4/CU).
// W: fp32 from global, hi/lo split inline, staged in LDS.
// PRE: 0 none; 1 relu(bn(x)); 2 relu(id + bn(x)) -> f1_out.
// INBF: input packed bf16 pairs. OUTBF: pack output to bf16 pairs.
// NOTE (r12 lesson): all activation I/O stays CACHED — L2/L3 forwards
// producer->consumer between nodes; non-temporal stores regressed 204->252.
// NOTE (r13 lesson): NO scatter-atomics in hot nodes — device-scope atomics
// retire at the LLC (~21 G/s); the histogram lives in prep_kernel now.
template<int PRE, int BIAS, int WTD, int OUTBF, int INBF>
__global__ __launch_bounds__(256, 4) void mm_kernel(
    const void*  __restrict__ inv_,  const float* __restrict__ identity,
    const float* __restrict__ Wg,    const float* __restrict__ bias,
    const float* __restrict__ gg,    const float* __restrict__ bb,
    const float* __restrict__ S_in,  float inv_denom,
    void*        __restrict__ outv,  float* __restrict__ S_out,
    const unsigned* __restrict__ cw, float* __restrict__ f1_out)
{
    __shared__ unsigned short lwh[64][72], lwl[64][72];   // padded W rows
    __shared__ float stg[4][16][68];                      // transpose staging
    __shared__ float sc[64], sh[64];
    __shared__ float LS[4][64], LQ[4][64];
    float* PS = &stg[0][0][0];                            // prologue overlay

    const int tid  = threadIdx.x;
    const int lane = tid & 63, wid = tid >> 6;
    const int l15  = lane & 15, kg = lane >> 4;
    const int brow = blockIdx.x * 64;
    const int arow = brow + wid * 16 + l15;

    // ---- issue ALL independent global loads up front ----
    const int wr = tid >> 2, wc = (tid & 3) * 16;
    const float4* wp = (const float4*)(Wg + wr * 64 + wc);
    float4 wv0 = wp[0], wv1 = wp[1], wv2 = wp[2], wv3 = wp[3];

    float xv[2][8];
    uint4 ub0, ub1;
    float4 a0, a1, a2, a3;
    if (INBF) {
        const uint4* ap = (const uint4*)((const unsigned*)inv_ +
                                         (size_t)arow * 32 + kg * 4);
        ub0 = ap[0]; ub1 = ap[4];
    } else {
        const float4* ap = (const float4*)((const float*)inv_ +
                                           (size_t)arow * 64 + kg * 8);
        a0 = ap[0]; a1 = ap[1]; a2 = ap[8]; a3 = ap[9];
    }
    float4 i0, i1, i2, i3;
    if (PRE == 2) {
        const float4* ip = (const float4*)(identity + (size_t)arow * 64 + kg * 8);
        i0 = ip[0]; i1 = ip[1]; i2 = ip[8]; i3 = ip[9];
    }
    uint4 cc;
    if (WTD) cc = ((const uint4*)(cw + brow + wid * 16))[kg];

    // ---- W split hi/lo -> LDS ----
    {
        float wf[16] = {wv0.x,wv0.y,wv0.z,wv0.w, wv1.x,wv1.y,wv1.z,wv1.w,
                        wv2.x,wv2.y,wv2.z,wv2.w, wv3.x,wv3.y,wv3.z,wv3.w};
        unsigned ph[8], pl[8];
        #pragma unroll
        for (int q = 0; q < 8; ++q) {
            unsigned short h0 = f2bf(wf[2*q]),   h1 = f2bf(wf[2*q+1]);
            unsigned short l0 = f2bf(wf[2*q]   - bf2f(h0));
            unsigned short l1 = f2bf(wf[2*q+1] - bf2f(h1));
            ph[q] = (unsigned)h0 | ((unsigned)h1 << 16);
            pl[q] = (unsigned)l0 | ((unsigned)l1 << 16);
        }
        uint4* dh = (uint4*)(&lwh[wr][wc]);
        uint4* dl = (uint4*)(&lwl[wr][wc]);
        dh[0] = make_uint4(ph[0], ph[1], ph[2], ph[3]);
        dh[1] = make_uint4(ph[4], ph[5], ph[6], ph[7]);
        dl[0] = make_uint4(pl[0], pl[1], pl[2], pl[3]);
        dl[1] = make_uint4(pl[4], pl[5], pl[6], pl[7]);
    }

    // ---- BN prologue: parallel shadow fold (all 256 threads) ----
    if (PRE >= 1) {
        const int idx = tid & 127, hh = tid >> 7;
        float acc = 0.f;
        #pragma unroll
        for (int g = 0; g < NSHD / 2; ++g)
            acc += S_in[(hh * (NSHD / 2) + g) * 128 + idx];
        PS[hh * 128 + idx] = acc;
        __syncthreads();
        if (tid < 128) PS[tid] += PS[128 + tid];
        __syncthreads();
        if (tid < 64) {
            float s = PS[tid], q = PS[64 + tid];
            float m   = s * inv_denom;
            float var = q * inv_denom - m * m;
            float scl = gg[tid] * rsqrtf(var + BN_EPS);
            sc[tid] = scl; sh[tid] = bb[tid] - m * scl;
        }
    }
    __syncthreads();

    // ---- assemble A ----
    if (INBF) {
        uint4 uu[2] = {ub0, ub1};
        #pragma unroll
        for (int ks = 0; ks < 2; ++ks) {
            unsigned w0 = uu[ks].x, w1 = uu[ks].y, w2 = uu[ks].z, w3 = uu[ks].w;
            xv[ks][0] = bf2f((unsigned short)(w0 & 0xffffu));
            xv[ks][1] = bf2f((unsigned short)(w0 >> 16));
            xv[ks][2] = bf2f((unsigned short)(w1 & 0xffffu));
            xv[ks][3] = bf2f((unsigned short)(w1 >> 16));
            xv[ks][4] = bf2f((unsigned short)(w2 & 0xffffu));
            xv[ks][5] = bf2f((unsigned short)(w2 >> 16));
            xv[ks][6] = bf2f((unsigned short)(w3 & 0xffffu));
            xv[ks][7] = bf2f((unsigned short)(w3 >> 16));
        }
    } else {
        xv[0][0]=a0.x; xv[0][1]=a0.y; xv[0][2]=a0.z; xv[0][3]=a0.w;
        xv[0][4]=a1.x; xv[0][5]=a1.y; xv[0][6]=a1.z; xv[0][7]=a1.w;
        xv[1][0]=a2.x; xv[1][1]=a2.y; xv[1][2]=a2.z; xv[1][3]=a2.w;
        xv[1][4]=a3.x; xv[1][5]=a3.y; xv[1][6]=a3.z; xv[1][7]=a3.w;
    }

    if (PRE == 1) {
        #pragma unroll
        for (int ks = 0; ks < 2; ++ks)
            #pragma unroll
            for (int j = 0; j < 8; ++j) {
                int k = ks * 32 + kg * 8 + j;
                xv[ks][j] = fmaxf(xv[ks][j] * sc[k] + sh[k], 0.f);
            }
    } else if (PRE == 2) {
        float idv[2][8];
        idv[0][0]=i0.x; idv[0][1]=i0.y; idv[0][2]=i0.z; idv[0][3]=i0.w;
        idv[0][4]=i1.x; idv[0][5]=i1.y; idv[0][6]=i1.z; idv[0][7]=i1.w;
        idv[1][0]=i2.x; idv[1][1]=i2.y; idv[1][2]=i2.z; idv[1][3]=i2.w;
        idv[1][4]=i3.x; idv[1][5]=i3.y; idv[1][6]=i3.z; idv[1][7]=i3.w;
        #pragma unroll
        for (int ks = 0; ks < 2; ++ks) {
            #pragma unroll
            for (int j = 0; j < 8; ++j) {
                int k = ks * 32 + kg * 8 + j;
                xv[ks][j] = fmaxf(idv[ks][j] + xv[ks][j] * sc[k] + sh[k], 0.f);
            }
            float* f1p = f1_out + (size_t)arow * 64 + kg * 8 + ks * 32;
            *(float4*)(f1p)     = make_float4(xv[ks][0], xv[ks][1], xv[ks][2], xv[ks][3]);
            *(float4*)(f1p + 4) = make_float4(xv[ks][4], xv[ks][5], xv[ks][6], xv[ks][7]);
        }
    }

    // ---- split A into hi+lo bf16; MFMA D = Ahi@Whi + Alo@Whi + Ahi@Wlo ----
    bf16x8 ahi[2], alo[2];
    #pragma unroll
    for (int ks = 0; ks < 2; ++ks) {
        bf16x8 th, tl;
        #pragma unroll
        for (int j = 0; j < 8; ++j) {
            unsigned short h = f2bf(xv[ks][j]);
            th[j] = (short)h;
            tl[j] = (short)f2bf(xv[ks][j] - bf2f(h));
        }
        ahi[ks] = th; alo[ks] = tl;
    }
    f32x4 d[4];
    #pragma unroll
    for (int ct = 0; ct < 4; ++ct) {
        float bc = BIAS ? bias[ct * 16 + l15] : 0.f;
        d[ct] = (f32x4){bc, bc, bc, bc};
    }
    #pragma unroll
    for (int ct = 0; ct < 4; ++ct) {
        const int gcol = ct * 16 + l15;
        #pragma unroll
        for (int ks = 0; ks < 2; ++ks) {
            bf16x8 wh = *(const bf16x8*)(&lwh[gcol][ks * 32 + kg * 8]);
            bf16x8 wl = *(const bf16x8*)(&lwl[gcol][ks * 32 + kg * 8]);
            d[ct] = __builtin_amdgcn_mfma_f32_16x16x32_bf16(ahi[ks], wh, d[ct], 0, 0, 0);
            d[ct] = __builtin_amdgcn_mfma_f32_16x16x32_bf16(alo[ks], wh, d[ct], 0, 0, 0);
            d[ct] = __builtin_amdgcn_mfma_f32_16x16x32_bf16(ahi[ks], wl, d[ct], 0, 0, 0);
        }
    }

    // ---- stats: D row = kg*4+i, col = ct*16+l15 ----
    float wt[4];
    #pragma unroll
    for (int i = 0; i < 4; ++i)
        wt[i] = WTD ? (float)((const unsigned*)&cc)[i] : 1.f;
    float ts[4], tq[4];
    #pragma unroll
    for (int ct = 0; ct < 4; ++ct) {
        float t = 0.f, t2 = 0.f;
        #pragma unroll
        for (int i = 0; i < 4; ++i) {
            float v = d[ct][i];
            t += wt[i] * v; t2 += wt[i] * v * v;
        }
        ts[ct] = t; tq[ct] = t2;
    }

    // ---- store via per-wave LDS transpose (overlays PS; prologue done) ----
    #pragma unroll
    for (int ct = 0; ct < 4; ++ct)
        #pragma unroll
        for (int i = 0; i < 4; ++i)
            stg[wid][kg * 4 + i][ct * 16 + l15] = d[ct][i];
    __syncthreads();
    if (!OUTBF) {
        float* op = (float*)outv + (size_t)arow * 64 + kg * 16;
        const float* srow = &stg[wid][l15][kg * 16];
        *(float4*)(op + 0)  = *(const float4*)(srow + 0);
        *(float4*)(op + 4)  = *(const float4*)(srow + 4);
        *(float4*)(op + 8)  = *(const float4*)(srow + 8);
        *(float4*)(op + 12) = *(const float4*)(srow + 12);
    } else {
        const float* srow = &stg[wid][l15][kg * 16];
        unsigned pk[8];
        #pragma unroll
        for (int q = 0; q < 8; ++q) pk[q] = pack2(srow[2 * q], srow[2 * q + 1]);
        unsigned* op = (unsigned*)outv;
        uint4* dst = (uint4*)(op + (size_t)arow * 32 + kg * 8);
        dst[0] = make_uint4(pk[0], pk[1], pk[2], pk[3]);
        dst[1] = make_uint4(pk[4], pk[5], pk[6], pk[7]);
    }

    // ---- cross-wave stats reduce + atomics (64 shadows) ----
    #pragma unroll
    for (int ct = 0; ct < 4; ++ct) {
        float a = ts[ct], b = tq[ct];
        a += __shfl_xor(a, 16);  a += __shfl_xor(a, 32);
        b += __shfl_xor(b, 16);  b += __shfl_xor(b, 32);
        if (kg == 0) { LS[wid][ct * 16 + l15] = a; LQ[wid][ct * 16 + l15] = b; }
    }
    __syncthreads();
    const int bsel = blockIdx.x & (NSHD - 1);
    if (tid < 64)
        atomicAdd(S_out + bsel * 128 + tid,
                  LS[0][tid] + LS[1][tid] + LS[2][tid] + LS[3][tid]);
    else if (tid < 128) {
        int c = tid - 64;
        atomicAdd(S_out + bsel * 128 + 64 + c,
                  LQ[0][c] + LQ[1][c] + LQ[2][c] + LQ[3][c]);
    }
}

// ---------------------------------------------------------------------------
// xm[r,c] = relu(bn(max_k y3[ref[r,k],c])), y3/xm bf16-packed (u32 = 2 ch).
// half-wave = one row; 2 row-pairs per wave; 32 loads in flight before
// the BN prologue. grid = 4096 blocks.
__global__ __launch_bounds__(256) void gather_kernel(
    const unsigned* __restrict__ y3u, const int* __restrict__ ref,
    const float* __restrict__ S_in, float inv_denom,
    const float* __restrict__ gg, const float* __restrict__ bb,
    unsigned* __restrict__ xmu, float* __restrict__ S_out)
{
    __shared__ float scs[64], shs[64], Rs[256], Rq[256], PS[256];
    const int tid = threadIdx.x;
    const int lane = tid & 63, wid = tid >> 6;
    const int c2 = lane & 31;
    const int hsel = lane & 32;                 // 0 or 32 -> even/odd row
    const int p0 = blockIdx.x * 8 + wid * 2;    // two row-pair units per wave
    const int r0 = 2 * p0 + (hsel ? 1 : 0);
    const int r1 = r0 + 2;

    int jv0 = ref[r0 * 16 + (lane & 15)];
    int jv1 = ref[r1 * 16 + (lane & 15)];
    unsigned u0[16], u1[16];
    #pragma unroll
    for (int t = 0; t < 16; ++t) {
        int j = __shfl(jv0, hsel + t);
        u0[t] = y3u[(size_t)j * 32 + c2];
    }
    #pragma unroll
    for (int t = 0; t < 16; ++t) {
        int j = __shfl(jv1, hsel + t);
        u1[t] = y3u[(size_t)j * 32 + c2];
    }

    // BN prologue: parallel shadow fold
    {
        const int idx = tid & 127, hh = tid >> 7;
        float acc = 0.f;
        #pragma unroll
        for (int g = 0; g < NSHD / 2; ++g)
            acc += S_in[(hh * (NSHD / 2) + g) * 128 + idx];
        PS[hh * 128 + idx] = acc;
        __syncthreads();
        if (tid < 128) PS[tid] += PS[128 + tid];
        __syncthreads();
        if (tid < 64) {
            float s = PS[tid], q = PS[64 + tid];
            float m   = s * inv_denom;
            float var = q * inv_denom - m * m;
            float scl = gg[tid] * rsqrtf(var + BN_EPS);
            scs[tid] = scl; shs[tid] = bb[tid] - m * scl;
        }
        __syncthreads();
    }
    const float sc0 = scs[2*c2], sc1 = scs[2*c2+1];
    const float sh0 = shs[2*c2], sh1 = shs[2*c2+1];

    float s0 = 0.f, q0 = 0.f, s1 = 0.f, q1 = 0.f;
    #pragma unroll
    for (int pair = 0; pair < 2; ++pair) {
        const unsigned* u = pair ? u1 : u0;
        const int r = pair ? r1 : r0;
        float m0 = bf2f((unsigned short)(u[0] & 0xffffu));
        float m1 = bf2f((unsigned short)(u[0] >> 16));
        #pragma unroll
        for (int t = 1; t < 16; ++t) {
            m0 = fmaxf(m0, bf2f((unsigned short)(u[t] & 0xffffu)));
            m1 = fmaxf(m1, bf2f((unsigned short)(u[t] >> 16)));
        }
        float x0 = fmaxf(m0 * sc0 + sh0, 0.f);  // bn monotone (gamma=1>0)
        float x1 = fmaxf(m1 * sc1 + sh1, 0.f);
        xmu[(size_t)r * 32 + c2] = pack2(x0, x1);
        s0 += x0; q0 += x0 * x0; s1 += x1; q1 += x1 * x1;
    }

    const int bsel = blockIdx.x & (NSHD - 1);
    Rs[tid] = s0; Rq[tid] = q0;
    __syncthreads();
    if (tid < 32) {
        float a = 0.f, c = 0.f;
        #pragma unroll
        for (int i = 0; i < 8; ++i) { a += Rs[tid + 32*i]; c += Rq[tid + 32*i]; }
        atomicAdd(S_out + bsel*128 + 2*tid, a);
        atomicAdd(S_out + bsel*128 + 64 + 2*tid, c);
    }
    __syncthreads();
    Rs[tid] = s1; Rq[tid] = q1;
    __syncthreads();
    if (tid < 32) {
        float a = 0.f, c = 0.f;
        #pragma unroll
        for (int i = 0; i < 8; ++i) { a += Rs[tid + 32*i]; c += Rq[tid + 32*i]; }
        atomicAdd(S_out + bsel*128 + 2*tid + 1, a);
        atomicAdd(S_out + bsel*128 + 64 + 2*tid + 1, c);
    }
}

// ---------------------------------------------------------------------------
// io = relu(io + y4*sc + sh)   (final residual, in place)
__global__ __launch_bounds__(256) void res_final(
    float* __restrict__ io, const float* __restrict__ y4,
    const float* __restrict__ S_in, float inv_denom,
    const float* __restrict__ gg, const float* __restrict__ bb)
{
    __shared__ float sc[64], sh[64], PS[256];
    const int tid = threadIdx.x;
    int i = blockIdx.x * 256 + tid;            // float4 index
    float4 idv = ((const float4*)io)[i];
    float4 yv  = ((const float4*)y4)[i];
    {
        const int idx = tid & 127, hh = tid >> 7;
        float acc = 0.f;
        #pragma unroll
        for (int g = 0; g < NSHD / 2; ++g)
            acc += S_in[(hh * (NSHD / 2) + g) * 128 + idx];
        PS[hh * 128 + idx] = acc;
        __syncthreads();
        if (tid < 128) PS[tid] += PS[128 + tid];
        __syncthreads();
        if (tid < 64) {
            float s = PS[tid], q = PS[64 + tid];
            float m   = s * inv_denom;
            float var = q * inv_denom - m * m;
            float scl = gg[tid] * rsqrtf(var + BN_EPS);
            sc[tid] = scl; sh[tid] = bb[tid] - m * scl;
        }
        __syncthreads();
    }
    int c0 = (i * 4) & 63;
    float4 o;
    o.x = fmaxf(idv.x + yv.x * sc[c0+0] + sh[c0+0], 0.f);
    o.y = fmaxf(idv.y + yv.y * sc[c0+1] + sh[c0+1], 0.f);
    o.z = fmaxf(idv.z + yv.z * sc[c0+2] + sh[c0+2], 0.f);
    o.w = fmaxf(idv.w + yv.w * sc[c0+3] + sh[c0+3], 0.f);
    ((float4*)io)[i] = o;
}

// ---------------------------------------------------------------------------
extern "C" void kernel_launch(void* const* d_in, const int* in_sizes, int n_in,
                              void* d_out, int out_size, void* d_ws, size_t ws_size,
                              hipStream_t stream)
{
    const float* feat    = (const float*)d_in[1];
    const int*   ref     = (const int*)  d_in[2];
    const float* fc1_w   = (const float*)d_in[3];
    const float* bn1_g   = (const float*)d_in[4];
    const float* bn1_b   = (const float*)d_in[5];
    const float* la_w1   = (const float*)d_in[6];
    const float* la_b1   = (const float*)d_in[7];
    const float* la_bn1g = (const float*)d_in[8];
    const float* la_bn1b = (const float*)d_in[9];
    const float* la_w2   = (const float*)d_in[10];
    const float* la_b2   = (const float*)d_in[11];
    const float* la_bn2g = (const float*)d_in[12];
    const float* la_bn2b = (const float*)d_in[13];
    const float* fc3_w   = (const float*)d_in[14];
    const float* bn2_g   = (const float*)d_in[15];
    const float* bn2_b   = (const float*)d_in[16];
    const float* bn3_g   = (const float*)d_in[17];
    const float* bn3_b   = (const float*)d_in[18];
    float* out = (float*)d_out;

    // ws: R1 16MB | R2 16MB | cnt 256KB | Sb 320KB
    char* base = (char*)d_ws;
    float*    R1  = (float*)base;
    float*    R2  = (float*)(base + 16u * 1024 * 1024);
    unsigned* cnt = (unsigned*)(base + 32u * 1024 * 1024);
    float*    Sb  = (float*)(cnt + N_PTS);
#define SS(i) (Sb + (i) * NSHD * 128)

    const float invN  = 1.f / (float)N_PTS;
    const float invNK = invN / 16.f;
    const int MMG = N_PTS / 64;   // 1024 blocks

    // prep: histogram (replicated scan, no global atomics) + zero stats
    prep_kernel<<<HBLK + 128, 512, 0, stream>>>(ref, cnt, Sb);

    // ---- block 0 ----
    mm_kernel<0,0,0,0,0><<<MMG,256,0,stream>>>(feat, nullptr, fc1_w,
        nullptr, nullptr, nullptr, nullptr, 0.f, R1, SS(0), nullptr, nullptr);
    mm_kernel<1,1,1,0,0><<<MMG,256,0,stream>>>(R1, nullptr, la_w1,
        la_b1, bn1_g, bn1_b, SS(0), invN, R2, SS(1), cnt, nullptr);
    mm_kernel<1,1,1,1,0><<<MMG,256,0,stream>>>(R2, nullptr, la_w2,
        la_b2, la_bn1g, la_bn1b, SS(1), invNK, R1, SS(2), cnt, nullptr);
    gather_kernel<<<4096,256,0,stream>>>((const unsigned*)R1, ref, SS(2), invNK,
        la_bn2g, la_bn2b, (unsigned*)R2, SS(3));
    mm_kernel<1,0,0,0,1><<<MMG,256,0,stream>>>(R2, nullptr, fc3_w,
        nullptr, bn2_g, bn2_b, SS(3), invN, R1, SS(4), nullptr, nullptr);

    // ---- block 1 (entry fuses block-0 residual; act0 -> out) ----
    mm_kernel<2,0,0,0,0><<<MMG,256,0,stream>>>(R1, feat, fc1_w + 4096,
        nullptr, bn3_g, bn3_b, SS(4), invN, R2, SS(5), nullptr, out);
    mm_kernel<1,1,1,0,0><<<MMG,256,0,stream>>>(R2, nullptr, la_w1 + 4096,
        la_b1 + 64, bn1_g + 64, bn1_b + 64, SS(5), invN, R1, SS(6), cnt, nullptr);
    mm_kernel<1,1,1,1,0><<<MMG,256,0,stream>>>(R1, nullptr, la_w2 + 4096,
        la_b2 + 64, la_bn1g + 64, la_bn1b + 64, SS(6), invNK, R2, SS(7), cnt, nullptr);
    gather_kernel<<<4096,256,0,stream>>>((const unsigned*)R2, ref, SS(7), invNK,
        la_bn2g + 64, la_bn2b + 64, (unsigned*)R1, SS(8));
    mm_kernel<1,0,0,0,1><<<MMG,256,0,stream>>>(R1, nullptr, fc3_w + 4096,
        nullptr, bn2_g + 64, bn2_b + 64, SS(8), invN, R2, SS(9), nullptr, nullptr);
    res_final<<<(N_PTS * 64 / 4) / 256, 256, 0, stream>>>(out, R2, SS(9), invN,
        bn3_g + 64, bn3_b + 64);
}

// Round 15
// 180.092 us; speedup vs baseline: 1.8795x; 1.8795x over previous
//
#include <hip/hip_runtime.h>

#define N_PTS 65536
#define BN_EPS 1e-5f
#define NSHD 64            // stat shadow copies
#define NSB  (10 * NSHD * 128)
#define HBLK 32            // histogram chunks (x2 bin-halves = 64 hist blocks)

typedef __attribute__((ext_vector_type(8))) short bf16x8;
typedef __attribute__((ext_vector_type(4))) float f32x4;

static __device__ __forceinline__ unsigned short f2bf(float f) {
    unsigned u = __builtin_bit_cast(unsigned, f);
    u += 0x7fffu + ((u >> 16) & 1u);          // round-to-nearest-even
    return (unsigned short)(u >> 16);
}
static __device__ __forceinline__ float bf2f(unsigned short h) {
    unsigned u = ((unsigned)h) << 16;
    return __builtin_bit_cast(float, u);
}
static __device__ __forceinline__ unsigned pack2(float a, float b) {
    return (unsigned)f2bf(a) | ((unsigned)f2bf(b) << 16);
}

// ---------------------------------------------------------------------------
// prep (replaces memset):
//  blocks [0, 2*HBLK): private-histogram build. Block (c = b>>1, h = b&1)
//    scans ITS OWN 32768-ref chunk (coalesced int4, 128 refs/thread) and
//    bins values in [h*32768, (h+1)*32768) into a 64 KB LDS u16 histogram
//    (u16-in-u32 LDS atomics; chunk 32768 < 65536 => exact, no overflow).
//    Plain-stores its half-histogram to H[c] (no global atomics).
//  blocks [2*HBLK, 2*HBLK+64): zero the stat-shadow buffer.
// r14 lesson: parallelize the SCAN (each block reads its own chunk), not the
// bins (r14's 32 blocks each scanning all 1M refs was 3%-occupancy disaster).
__global__ __launch_bounds__(256) void prep_kernel(
    const int* __restrict__ ref, unsigned short* __restrict__ H,
    float* __restrict__ Sb)
{
    const int b = blockIdx.x, tid = threadIdx.x;
    if (b < 2 * HBLK) {
        __shared__ unsigned bins[16384];          // 32768 u16 halves = 64 KB
        const int c = b >> 1, h = b & 1;
        const int lo = h * 32768;
        #pragma unroll
        for (int i = 0; i < 64; ++i) bins[tid + i * 256] = 0u;
        __syncthreads();
        const int4* rp = (const int4*)(ref + c * 32768);
        #pragma unroll 4
        for (int i = 0; i < 32; ++i) {
            int4 v = rp[tid + i * 256];
            unsigned x;
            x = (unsigned)(v.x - lo);
            if (x < 32768u) atomicAdd(&bins[x >> 1], 1u << (16 * (x & 1)));
            x = (unsigned)(v.y - lo);
            if (x < 32768u) atomicAdd(&bins[x >> 1], 1u << (16 * (x & 1)));
            x = (unsigned)(v.z - lo);
            if (x < 32768u) atomicAdd(&bins[x >> 1], 1u << (16 * (x & 1)));
            x = (unsigned)(v.w - lo);
            if (x < 32768u) atomicAdd(&bins[x >> 1], 1u << (16 * (x & 1)));
        }
        __syncthreads();
        unsigned* dst = (unsigned*)(H + (size_t)c * 65536 + lo);
        #pragma unroll
        for (int i = 0; i < 64; ++i) dst[tid + i * 256] = bins[tid + i * 256];
    } else {
        const int zidx = (b - 2 * HBLK) * 256 + tid;
        for (int i = zidx; i < NSB; i += 64 * 256) Sb[i] = 0.f;
    }
}

// ---------------------------------------------------------------------------
// Fused (pre-op) -> 64x64 matmul (bf16x3 MFMA, ~fp32) -> (weighted) stats.
// Wave = 16 rows x 64 cols. Block = 4 waves = 64 rows. Grid = 1024 (4/CU).
// W: fp32 from global, hi/lo split inline, staged in LDS.
// PRE: 0 none; 1 relu(bn(x)); 2 relu(id + bn(x)) -> f1_out.
// INBF: input packed bf16 pairs. OUTBF: pack output to bf16 pairs.
// MERGE: fold the 32 private histograms into cnt (threads 0..63, 1 bin each).
// r12 lesson: activation I/O stays CACHED (L2/L3 forwards producer->consumer).
// r13 lesson: no scatter-atomics in hot nodes (LLC RMW ~21 G/s).
template<int PRE, int BIAS, int WTD, int OUTBF, int INBF, int MERGE>
__global__ __launch_bounds__(256, 4) void mm_kernel(
    const void*  __restrict__ inv_,  const float* __restrict__ identity,
    const float* __restrict__ Wg,    const float* __restrict__ bias,
    const float* __restrict__ gg,    const float* __restrict__ bb,
    const float* __restrict__ S_in,  float inv_denom,
    void*        __restrict__ outv,  float* __restrict__ S_out,
    const unsigned* __restrict__ cw, float* __restrict__ f1_out,
    const unsigned short* __restrict__ hsrc, unsigned* __restrict__ hdst)
{
    __shared__ unsigned short lwh[64][72], lwl[64][72];   // padded W rows
    __shared__ float stg[4][16][68];                      // transpose staging
    __shared__ float sc[64], sh[64];
    __shared__ float LS[4][64], LQ[4][64];
    float* PS = &stg[0][0][0];                            // prologue overlay

    const int tid  = threadIdx.x;
    const int lane = tid & 63, wid = tid >> 6;
    const int l15  = lane & 15, kg = lane >> 4;
    const int brow = blockIdx.x * 64;
    const int arow = brow + wid * 16 + l15;

    // ---- issue ALL independent global loads up front ----
    const int wr = tid >> 2, wc = (tid & 3) * 16;
    const float4* wp = (const float4*)(Wg + wr * 64 + wc);
    float4 wv0 = wp[0], wv1 = wp[1], wv2 = wp[2], wv3 = wp[3];

    float xv[2][8];
    uint4 ub0, ub1;
    float4 a0, a1, a2, a3;
    if (INBF) {
        const uint4* ap = (const uint4*)((const unsigned*)inv_ +
                                         (size_t)arow * 32 + kg * 4);
        ub0 = ap[0]; ub1 = ap[4];
    } else {
        const float4* ap = (const float4*)((const float*)inv_ +
                                           (size_t)arow * 64 + kg * 8);
        a0 = ap[0]; a1 = ap[1]; a2 = ap[8]; a3 = ap[9];
    }
    float4 i0, i1, i2, i3;
    if (PRE == 2) {
        const float4* ip = (const float4*)(identity + (size_t)arow * 64 + kg * 8);
        i0 = ip[0]; i1 = ip[1]; i2 = ip[8]; i3 = ip[9];
    }
    uint4 cc;
    if (WTD) cc = ((const uint4*)(cw + brow + wid * 16))[kg];

    // ---- histogram merge: 64 threads x 1 bin, 32 private u16 hists ----
    if (MERGE) {
        if (tid < 64) {
            const int bin = blockIdx.x * 64 + tid;
            unsigned s = 0;
            #pragma unroll
            for (int g = 0; g < HBLK; ++g)
                s += (unsigned)hsrc[(size_t)g * 65536 + bin];
            hdst[bin] = s;
        }
    }

    // ---- W split hi/lo -> LDS ----
    {
        float wf[16] = {wv0.x,wv0.y,wv0.z,wv0.w, wv1.x,wv1.y,wv1.z,wv1.w,
                        wv2.x,wv2.y,wv2.z,wv2.w, wv3.x,wv3.y,wv3.z,wv3.w};
        unsigned ph[8], pl[8];
        #pragma unroll
        for (int q = 0; q < 8; ++q) {
            unsigned short h0 = f2bf(wf[2*q]),   h1 = f2bf(wf[2*q+1]);
            unsigned short l0 = f2bf(wf[2*q]   - bf2f(h0));
            unsigned short l1 = f2bf(wf[2*q+1] - bf2f(h1));
            ph[q] = (unsigned)h0 | ((unsigned)h1 << 16);
            pl[q] = (unsigned)l0 | ((unsigned)l1 << 16);
        }
        uint4* dh = (uint4*)(&lwh[wr][wc]);
        uint4* dl = (uint4*)(&lwl[wr][wc]);
        dh[0] = make_uint4(ph[0], ph[1], ph[2], ph[3]);
        dh[1] = make_uint4(ph[4], ph[5], ph[6], ph[7]);
        dl[0] = make_uint4(pl[0], pl[1], pl[2], pl[3]);
        dl[1] = make_uint4(pl[4], pl[5], pl[6], pl[7]);
    }

    // ---- BN prologue: parallel shadow fold (all 256 threads) ----
    if (PRE >= 1) {
        const int idx = tid & 127, hh = tid >> 7;
        float acc = 0.f;
        #pragma unroll
        for (int g = 0; g < NSHD / 2; ++g)
            acc += S_in[(hh * (NSHD / 2) + g) * 128 + idx];
        PS[hh * 128 + idx] = acc;
        __syncthreads();
        if (tid < 128) PS[tid] += PS[128 + tid];
        __syncthreads();
        if (tid < 64) {
            float s = PS[tid], q = PS[64 + tid];
            float m   = s * inv_denom;
            float var = q * inv_denom - m * m;
            float scl = gg[tid] * rsqrtf(var + BN_EPS);
            sc[tid] = scl; sh[tid] = bb[tid] - m * scl;
        }
    }
    __syncthreads();

    // ---- assemble A ----
    if (INBF) {
        uint4 uu[2] = {ub0, ub1};
        #pragma unroll
        for (int ks = 0; ks < 2; ++ks) {
            unsigned w0 = uu[ks].x, w1 = uu[ks].y, w2 = uu[ks].z, w3 = uu[ks].w;
            xv[ks][0] = bf2f((unsigned short)(w0 & 0xffffu));
            xv[ks][1] = bf2f((unsigned short)(w0 >> 16));
            xv[ks][2] = bf2f((unsigned short)(w1 & 0xffffu));
            xv[ks][3] = bf2f((unsigned short)(w1 >> 16));
            xv[ks][4] = bf2f((unsigned short)(w2 & 0xffffu));
            xv[ks][5] = bf2f((unsigned short)(w2 >> 16));
            xv[ks][6] = bf2f((unsigned short)(w3 & 0xffffu));
            xv[ks][7] = bf2f((unsigned short)(w3 >> 16));
        }
    } else {
        xv[0][0]=a0.x; xv[0][1]=a0.y; xv[0][2]=a0.z; xv[0][3]=a0.w;
        xv[0][4]=a1.x; xv[0][5]=a1.y; xv[0][6]=a1.z; xv[0][7]=a1.w;
        xv[1][0]=a2.x; xv[1][1]=a2.y; xv[1][2]=a2.z; xv[1][3]=a2.w;
        xv[1][4]=a3.x; xv[1][5]=a3.y; xv[1][6]=a3.z; xv[1][7]=a3.w;
    }

    if (PRE == 1) {
        #pragma unroll
        for (int ks = 0; ks < 2; ++ks)
            #pragma unroll
            for (int j = 0; j < 8; ++j) {
                int k = ks * 32 + kg * 8 + j;
                xv[ks][j] = fmaxf(xv[ks][j] * sc[k] + sh[k], 0.f);
            }
    } else if (PRE == 2) {
        float idv[2][8];
        idv[0][0]=i0.x; idv[0][1]=i0.y; idv[0][2]=i0.z; idv[0][3]=i0.w;
        idv[0][4]=i1.x; idv[0][5]=i1.y; idv[0][6]=i1.z; idv[0][7]=i1.w;
        idv[1][0]=i2.x; idv[1][1]=i2.y; idv[1][2]=i2.z; idv[1][3]=i2.w;
        idv[1][4]=i3.x; idv[1][5]=i3.y; idv[1][6]=i3.z; idv[1][7]=i3.w;
        #pragma unroll
        for (int ks = 0; ks < 2; ++ks) {
            #pragma unroll
            for (int j = 0; j < 8; ++j) {
                int k = ks * 32 + kg * 8 + j;
                xv[ks][j] = fmaxf(idv[ks][j] + xv[ks][j] * sc[k] + sh[k], 0.f);
            }
            float* f1p = f1_out + (size_t)arow * 64 + kg * 8 + ks * 32;
            *(float4*)(f1p)     = make_float4(xv[ks][0], xv[ks][1], xv[ks][2], xv[ks][3]);
            *(float4*)(f1p + 4) = make_float4(xv[ks][4], xv[ks][5], xv[ks][6], xv[ks][7]);
        }
    }

    // ---- split A into hi+lo bf16; MFMA D = Ahi@Whi + Alo@Whi + Ahi@Wlo ----
    bf16x8 ahi[2], alo[2];
    #pragma unroll
    for (int ks = 0; ks < 2; ++ks) {
        bf16x8 th, tl;
        #pragma unroll
        for (int j = 0; j < 8; ++j) {
            unsigned short h = f2bf(xv[ks][j]);
            th[j] = (short)h;
            tl[j] = (short)f2bf(xv[ks][j] - bf2f(h));
        }
        ahi[ks] = th; alo[ks] = tl;
    }
    f32x4 d[4];
    #pragma unroll
    for (int ct = 0; ct < 4; ++ct) {
        float bc = BIAS ? bias[ct * 16 + l15] : 0.f;
        d[ct] = (f32x4){bc, bc, bc, bc};
    }
    #pragma unroll
    for (int ct = 0; ct < 4; ++ct) {
        const int gcol = ct * 16 + l15;
        #pragma unroll
        for (int ks = 0; ks < 2; ++ks) {
            bf16x8 wh = *(const bf16x8*)(&lwh[gcol][ks * 32 + kg * 8]);
            bf16x8 wl = *(const bf16x8*)(&lwl[gcol][ks * 32 + kg * 8]);
            d[ct] = __builtin_amdgcn_mfma_f32_16x16x32_bf16(ahi[ks], wh, d[ct], 0, 0, 0);
            d[ct] = __builtin_amdgcn_mfma_f32_16x16x32_bf16(alo[ks], wh, d[ct], 0, 0, 0);
            d[ct] = __builtin_amdgcn_mfma_f32_16x16x32_bf16(ahi[ks], wl, d[ct], 0, 0, 0);
        }
    }

    // ---- stats: D row = kg*4+i, col = ct*16+l15 ----
    float wt[4];
    #pragma unroll
    for (int i = 0; i < 4; ++i)
        wt[i] = WTD ? (float)((const unsigned*)&cc)[i] : 1.f;
    float ts[4], tq[4];
    #pragma unroll
    for (int ct = 0; ct < 4; ++ct) {
        float t = 0.f, t2 = 0.f;
        #pragma unroll
        for (int i = 0; i < 4; ++i) {
            float v = d[ct][i];
            t += wt[i] * v; t2 += wt[i] * v * v;
        }
        ts[ct] = t; tq[ct] = t2;
    }

    // ---- store via per-wave LDS transpose (overlays PS; prologue done) ----
    #pragma unroll
    for (int ct = 0; ct < 4; ++ct)
        #pragma unroll
        for (int i = 0; i < 4; ++i)
            stg[wid][kg * 4 + i][ct * 16 + l15] = d[ct][i];
    __syncthreads();
    if (!OUTBF) {
        float* op = (float*)outv + (size_t)arow * 64 + kg * 16;
        const float* srow = &stg[wid][l15][kg * 16];
        *(float4*)(op + 0)  = *(const float4*)(srow + 0);
        *(float4*)(op + 4)  = *(const float4*)(srow + 4);
        *(float4*)(op + 8)  = *(const float4*)(srow + 8);
        *(float4*)(op + 12) = *(const float4*)(srow + 12);
    } else {
        const float* srow = &stg[wid][l15][kg * 16];
        unsigned pk[8];
        #pragma unroll
        for (int q = 0; q < 8; ++q) pk[q] = pack2(srow[2 * q], srow[2 * q + 1]);
        unsigned* op = (unsigned*)outv;
        uint4* dst = (uint4*)(op + (size_t)arow * 32 + kg * 8);
        dst[0] = make_uint4(pk[0], pk[1], pk[2], pk[3]);
        dst[1] = make_uint4(pk[4], pk[5], pk[6], pk[7]);
    }

    // ---- cross-wave stats reduce + atomics (64 shadows) ----
    #pragma unroll
    for (int ct = 0; ct < 4; ++ct) {
        float a = ts[ct], b = tq[ct];
        a += __shfl_xor(a, 16);  a += __shfl_xor(a, 32);
        b += __shfl_xor(b, 16);  b += __shfl_xor(b, 32);
        if (kg == 0) { LS[wid][ct * 16 + l15] = a; LQ[wid][ct * 16 + l15] = b; }
    }
    __syncthreads();
    const int bsel = blockIdx.x & (NSHD - 1);
    if (tid < 64)
        atomicAdd(S_out + bsel * 128 + tid,
                  LS[0][tid] + LS[1][tid] + LS[2][tid] + LS[3][tid]);
    else if (tid < 128) {
        int c = tid - 64;
        atomicAdd(S_out + bsel * 128 + 64 + c,
                  LQ[0][c] + LQ[1][c] + LQ[2][c] + LQ[3][c]);
    }
}

// ---------------------------------------------------------------------------
// xm[r,c] = relu(bn(max_k y3[ref[r,k],c])), y3/xm bf16-packed (u32 = 2 ch).
// half-wave = one row; 2 row-pairs per wave; 32 loads in flight before
// the BN prologue. grid = 4096 blocks.
__global__ __launch_bounds__(256) void gather_kernel(
    const unsigned* __restrict__ y3u, const int* __restrict__ ref,
    const float* __restrict__ S_in, float inv_denom,
    const float* __restrict__ gg, const float* __restrict__ bb,
    unsigned* __restrict__ xmu, float* __restrict__ S_out)
{
    __shared__ float scs[64], shs[64], Rs[256], Rq[256], PS[256];
    const int tid = threadIdx.x;
    const int lane = tid & 63, wid = tid >> 6;
    const int c2 = lane & 31;
    const int hsel = lane & 32;                 // 0 or 32 -> even/odd row
    const int p0 = blockIdx.x * 8 + wid * 2;    // two row-pair units per wave
    const int r0 = 2 * p0 + (hsel ? 1 : 0);
    const int r1 = r0 + 2;

    int jv0 = ref[r0 * 16 + (lane & 15)];
    int jv1 = ref[r1 * 16 + (lane & 15)];
    unsigned u0[16], u1[16];
    #pragma unroll
    for (int t = 0; t < 16; ++t) {
        int j = __shfl(jv0, hsel + t);
        u0[t] = y3u[(size_t)j * 32 + c2];
    }
    #pragma unroll
    for (int t = 0; t < 16; ++t) {
        int j = __shfl(jv1, hsel + t);
        u1[t] = y3u[(size_t)j * 32 + c2];
    }

    // BN prologue: parallel shadow fold
    {
        const int idx = tid & 127, hh = tid >> 7;
        float acc = 0.f;
        #pragma unroll
        for (int g = 0; g < NSHD / 2; ++g)
            acc += S_in[(hh * (NSHD / 2) + g) * 128 + idx];
        PS[hh * 128 + idx] = acc;
        __syncthreads();
        if (tid < 128) PS[tid] += PS[128 + tid];
        __syncthreads();
        if (tid < 64) {
            float s = PS[tid], q = PS[64 + tid];
            float m   = s * inv_denom;
            float var = q * inv_denom - m * m;
            float scl = gg[tid] * rsqrtf(var + BN_EPS);
            scs[tid] = scl; shs[tid] = bb[tid] - m * scl;
        }
        __syncthreads();
    }
    const float sc0 = scs[2*c2], sc1 = scs[2*c2+1];
    const float sh0 = shs[2*c2], sh1 = shs[2*c2+1];

    float s0 = 0.f, q0 = 0.f, s1 = 0.f, q1 = 0.f;
    #pragma unroll
    for (int pair = 0; pair < 2; ++pair) {
        const unsigned* u = pair ? u1 : u0;
        const int r = pair ? r1 : r0;
        float m0 = bf2f((unsigned short)(u[0] & 0xffffu));
        float m1 = bf2f((unsigned short)(u[0] >> 16));
        #pragma unroll
        for (int t = 1; t < 16; ++t) {
            m0 = fmaxf(m0, bf2f((unsigned short)(u[t] & 0xffffu)));
            m1 = fmaxf(m1, bf2f((unsigned short)(u[t] >> 16)));
        }
        float x0 = fmaxf(m0 * sc0 + sh0, 0.f);  // bn monotone (gamma=1>0)
        float x1 = fmaxf(m1 * sc1 + sh1, 0.f);
        xmu[(size_t)r * 32 + c2] = pack2(x0, x1);
        s0 += x0; q0 += x0 * x0; s1 += x1; q1 += x1 * x1;
    }

    const int bsel = blockIdx.x & (NSHD - 1);
    Rs[tid] = s0; Rq[tid] = q0;
    __syncthreads();
    if (tid < 32) {
        float a = 0.f, c = 0.f;
        #pragma unroll
        for (int i = 0; i < 8; ++i) { a += Rs[tid + 32*i]; c += Rq[tid + 32*i]; }
        atomicAdd(S_out + bsel*128 + 2*tid, a);
        atomicAdd(S_out + bsel*128 + 64 + 2*tid, c);
    }
    __syncthreads();
    Rs[tid] = s1; Rq[tid] = q1;
    __syncthreads();
    if (tid < 32) {
        float a = 0.f, c = 0.f;
        #pragma unroll
        for (int i = 0; i < 8; ++i) { a += Rs[tid + 32*i]; c += Rq[tid + 32*i]; }
        atomicAdd(S_out + bsel*128 + 2*tid + 1, a);
        atomicAdd(S_out + bsel*128 + 64 + 2*tid + 1, c);
    }
}

// ---------------------------------------------------------------------------
// io = relu(io + y4*sc + sh)   (final residual, in place)
__global__ __launch_bounds__(256) void res_final(
    float* __restrict__ io, const float* __restrict__ y4,
    const float* __restrict__ S_in, float inv_denom,
    const float* __restrict__ gg, const float* __restrict__ bb)
{
    __shared__ float sc[64], sh[64], PS[256];
    const int tid = threadIdx.x;
    int i = blockIdx.x * 256 + tid;            // float4 index
    float4 idv = ((const float4*)io)[i];
    float4 yv  = ((const float4*)y4)[i];
    {
        const int idx = tid & 127, hh = tid >> 7;
        float acc = 0.f;
        #pragma unroll
        for (int g = 0; g < NSHD / 2; ++g)
            acc += S_in[(hh * (NSHD / 2) + g) * 128 + idx];
        PS[hh * 128 + idx] = acc;
        __syncthreads();
        if (tid < 128) PS[tid] += PS[128 + tid];
        __syncthreads();
        if (tid < 64) {
            float s = PS[tid], q = PS[64 + tid];
            float m   = s * inv_denom;
            float var = q * inv_denom - m * m;
            float scl = gg[tid] * rsqrtf(var + BN_EPS);
            sc[tid] = scl; sh[tid] = bb[tid] - m * scl;
        }
        __syncthreads();
    }
    int c0 = (i * 4) & 63;
    float4 o;
    o.x = fmaxf(idv.x + yv.x * sc[c0+0] + sh[c0+0], 0.f);
    o.y = fmaxf(idv.y + yv.y * sc[c0+1] + sh[c0+1], 0.f);
    o.z = fmaxf(idv.z + yv.z * sc[c0+2] + sh[c0+2], 0.f);
    o.w = fmaxf(idv.w + yv.w * sc[c0+3] + sh[c0+3], 0.f);
    ((float4*)io)[i] = o;
}

// ---------------------------------------------------------------------------
extern "C" void kernel_launch(void* const* d_in, const int* in_sizes, int n_in,
                              void* d_out, int out_size, void* d_ws, size_t ws_size,
                              hipStream_t stream)
{
    const float* feat    = (const float*)d_in[1];
    const int*   ref     = (const int*)  d_in[2];
    const float* fc1_w   = (const float*)d_in[3];
    const float* bn1_g   = (const float*)d_in[4];
    const float* bn1_b   = (const float*)d_in[5];
    const float* la_w1   = (const float*)d_in[6];
    const float* la_b1   = (const float*)d_in[7];
    const float* la_bn1g = (const float*)d_in[8];
    const float* la_bn1b = (const float*)d_in[9];
    const float* la_w2   = (const float*)d_in[10];
    const float* la_b2   = (const float*)d_in[11];
    const float* la_bn2g = (const float*)d_in[12];
    const float* la_bn2b = (const float*)d_in[13];
    const float* fc3_w   = (const float*)d_in[14];
    const float* bn2_g   = (const float*)d_in[15];
    const float* bn2_b   = (const float*)d_in[16];
    const float* bn3_g   = (const float*)d_in[17];
    const float* bn3_b   = (const float*)d_in[18];
    float* out = (float*)d_out;

    // ws: R1 16MB | R2 16MB | cnt 256KB | Sb 320KB
    // H (32 private u16 histograms, 4MB) aliases R2 (dead until node B0).
    char* base = (char*)d_ws;
    float*    R1  = (float*)base;
    float*    R2  = (float*)(base + 16u * 1024 * 1024);
    unsigned* cnt = (unsigned*)(base + 32u * 1024 * 1024);
    float*    Sb  = (float*)(cnt + N_PTS);
    unsigned short* H = (unsigned short*)R2;
#define SS(i) (Sb + (i) * NSHD * 128)

    const float invN  = 1.f / (float)N_PTS;
    const float invNK = invN / 16.f;
    const int MMG = N_PTS / 64;   // 1024 blocks

    // prep: 64 chunked private histograms (exact, no global atomics) + zero Sb
    prep_kernel<<<2 * HBLK + 64, 256, 0, stream>>>(ref, H, Sb);

    // ---- block 0 ----
    mm_kernel<0,0,0,0,0,1><<<MMG,256,0,stream>>>(feat, nullptr, fc1_w,
        nullptr, nullptr, nullptr, nullptr, 0.f, R1, SS(0), nullptr, nullptr, H, cnt);
    mm_kernel<1,1,1,0,0,0><<<MMG,256,0,stream>>>(R1, nullptr, la_w1,
        la_b1, bn1_g, bn1_b, SS(0), invN, R2, SS(1), cnt, nullptr, nullptr, nullptr);
    mm_kernel<1,1,1,1,0,0><<<MMG,256,0,stream>>>(R2, nullptr, la_w2,
        la_b2, la_bn1g, la_bn1b, SS(1), invNK, R1, SS(2), cnt, nullptr, nullptr, nullptr);
    gather_kernel<<<4096,256,0,stream>>>((const unsigned*)R1, ref, SS(2), invNK,
        la_bn2g, la_bn2b, (unsigned*)R2, SS(3));
    mm_kernel<1,0,0,0,1,0><<<MMG,256,0,stream>>>(R2, nullptr, fc3_w,
        nullptr, bn2_g, bn2_b, SS(3), invN, R1, SS(4), nullptr, nullptr, nullptr, nullptr);

    // ---- block 1 (entry fuses block-0 residual; act0 -> out) ----
    mm_kernel<2,0,0,0,0,0><<<MMG,256,0,stream>>>(R1, feat, fc1_w + 4096,
        nullptr, bn3_g, bn3_b, SS(4), invN, R2, SS(5), nullptr, out, nullptr, nullptr);
    mm_kernel<1,1,1,0,0,0><<<MMG,256,0,stream>>>(R2, nullptr, la_w1 + 4096,
        la_b1 + 64, bn1_g + 64, bn1_b + 64, SS(5), invN, R1, SS(6), cnt, nullptr, nullptr, nullptr);
    mm_kernel<1,1,1,1,0,0><<<MMG,256,0,stream>>>(R1, nullptr, la_w2 + 4096,
        la_b2 + 64, la_bn1g + 64, la_bn1b + 64, SS(6), invNK, R2, SS(7), cnt, nullptr, nullptr, nullptr);
    gather_kernel<<<4096,256,0,stream>>>((const unsigned*)R2, ref, SS(7), invNK,
        la_bn2g + 64, la_bn2b + 64, (unsigned*)R1, SS(8));
    mm_kernel<1,0,0,0,1,0><<<MMG,256,0,stream>>>(R1, nullptr, fc3_w + 4096,
        nullptr, bn2_g + 64, bn2_b + 64, SS(8), invN, R2, SS(9), nullptr, nullptr, nullptr, nullptr);
    res_final<<<(N_PTS * 64 / 4) / 256, 256, 0, stream>>>(out, R2, SS(9), invN,
        bn3_g + 64, bn3_b + 64);
}